// Round 7
// baseline (1106.133 us; speedup 1.0000x reference)
//
#include <hip/hip_runtime.h>

// Deformable bottleneck block, MI355X/gfx950.  Round 7.
// G1: same verified 4-sub-phase skeleton/ledger as round 6, MFMA switched to
// 32x32x16 (1015 vs 845 FLOP/cyc/SIMD -> -17% MFMA-pipe cycles; identical LDS
// image/staging/vmcnt). Epilogue uses the m74/m101 32x32 C/D map.
// Prep: 6 packs + prep_x + xp-border fused into one mega_prep launch; border-
// only zero for t1p/h2p/t2p after D1 (t1p aliases off1). 16 -> 11 dispatches.

typedef unsigned short u16;
typedef __bf16 bf16x8 __attribute__((ext_vector_type(8)));
typedef float f32x4 __attribute__((ext_vector_type(4)));
typedef float f32x16 __attribute__((ext_vector_type(16)));
typedef _Float16 f16;

__device__ __forceinline__ u16 f2bf(float f) {
  unsigned u = __float_as_uint(f);
  u += 0x7fffu + ((u >> 16) & 1u);
  return (u16)(u >> 16);
}
__device__ __forceinline__ float bf2f(u16 h) { return __uint_as_float((unsigned)h << 16); }
__device__ __forceinline__ u16 f2h(float f) { f16 h = (f16)f; return __builtin_bit_cast(u16, h); }
__device__ __forceinline__ float h2f(u16 u) { return (float)__builtin_bit_cast(f16, u); }

__device__ __forceinline__ void gload16(const u16* g, u16* l) {
  __builtin_amdgcn_global_load_lds((__attribute__((address_space(1))) unsigned int*)g,
                                   (__attribute__((address_space(3))) unsigned int*)l,
                                   16, 0, 0);
}

#define VM8() asm volatile("s_waitcnt vmcnt(8)" ::: "memory")
#define VM6() asm volatile("s_waitcnt vmcnt(6)" ::: "memory")
#define VM0() asm volatile("s_waitcnt vmcnt(0)" ::: "memory")
#define BAR()                                   \
  do {                                          \
    asm volatile("" ::: "memory");              \
    __builtin_amdgcn_s_barrier();               \
    asm volatile("" ::: "memory");              \
  } while (0)
#define LGK0()                                          \
  do {                                                  \
    asm volatile("s_waitcnt lgkmcnt(0)" ::: "memory");  \
    __builtin_amdgcn_sched_barrier(0);                  \
  } while (0)
#define SB0() __builtin_amdgcn_sched_barrier(0)

// ---- device pack helpers ----
// 128^2-kernel layout: [M/128][K/32][kg][m][8], K tap-major.
__device__ __forceinline__ void d_pack_w(const float* __restrict__ w, u16* __restrict__ hi,
                                         int C, int T, int id) {
  const int AK = C * T;
  const int j = id & 7;
  const int slot = (id >> 3) & 511;
  const int rest = id >> 12;
  const int steps = AK >> 5;
  const int step = rest % steps;
  const int mt = rest / steps;
  const int kg = slot >> 7, m = slot & 127;
  const int k = step * 32 + kg * 8 + j;
  const int tap = k / C;
  const int c = k - tap * C;
  const int mg = mt * 128 + m;
  hi[id] = f2bf(w[((size_t)mg * C + c) * T + tap]);
}

// 256^2-kernel layout: [mt][half H][row][kq][8], read-XOR baked in. CC=1024,T=9.
__device__ __forceinline__ void d_pack8_ow1(const float* __restrict__ w, u16* __restrict__ dst,
                                            int id) {
  constexpr int CC = 1024, T = 9;
  constexpr int KT2 = 2 * (T * CC / 64);   // 288
  const int j = id & 7;
  const int d = (id >> 3) & 1023;
  const int rest = id >> 13;
  const int H = rest % KT2;
  const int mt = rest / KT2;
  const int row = d >> 2, kq = d & 3;
  const int k = H * 32 + ((kq ^ ((row >> 1) & 3)) * 8) + j;
  const int tap = k / CC, c = k - tap * CC;
  const int oc = mt * 256 + row;
  dst[id] = f2bf(w[((size_t)oc * CC + c) * T + tap]);
}

// ---- fused prep: all packs + x pad/transpose + xp border zero, one launch ----
// ranges (blocks of 256): [0,4096) prep_x | [4096,8256) xp border |
// [8256,81984) pack8 ow1 | [81984,83008) w1 | [83008,87616) ow2 |
// [87616,89920) w2 | [89920,94528) ow3 | [94528,95552) w3
__global__ __launch_bounds__(256) void mega_prep(
    const float* __restrict__ x, u16* __restrict__ xp,
    const float* __restrict__ ow1, u16* __restrict__ dow1,
    const float* __restrict__ w1, u16* __restrict__ dw1,
    const float* __restrict__ ow2, u16* __restrict__ dow2,
    const float* __restrict__ w2, u16* __restrict__ dw2,
    const float* __restrict__ ow3, u16* __restrict__ dow3,
    const float* __restrict__ w3, u16* __restrict__ dw3) {
  __shared__ float t[64][65];
  const int bb = blockIdx.x;
  const int tid = threadIdx.x;
  if (bb < 4096) {
    // prep_x: NCHW fp32 -> padded bf16 [4][66][66][1024] interior
    const int c0 = (bb & 15) * 64;
    const int y = (bb >> 4) & 63;
    const int b = bb >> 10;
#pragma unroll
    for (int i = 0; i < 16; ++i) {
      const int idx = i * 256 + tid;
      const int ci = idx >> 6, xi = idx & 63;
      t[ci][xi] = x[(((size_t)b * 1024 + c0 + ci) * 64 + y) * 64 + xi];
    }
    __syncthreads();
#pragma unroll
    for (int i = 0; i < 16; ++i) {
      const int idx = i * 256 + tid;
      const int xi = idx >> 6, ci = idx & 63;
      xp[((size_t)((b * 66 + y + 1) * 66 + (xi + 1))) * 1024 + c0 + ci] = f2bf(t[ci][xi]);
    }
  } else if (bb < 8256) {
    // xp border zero: 4 img x 260 border px x 1024 ch
    const int id = (bb - 4096) * 256 + tid;
    const int c = id & 1023;
    const int p = id >> 10;
    const int b = p / 260;
    const int pi = p - b * 260;
    int y, xx;
    if (pi < 66) { y = 0; xx = pi; }
    else if (pi < 132) { y = 65; xx = pi - 66; }
    else { const int q = pi - 132; y = 1 + (q >> 1); xx = (q & 1) * 65; }
    xp[((size_t)((b * 66 + y) * 66 + xx)) * 1024 + c] = 0;
  } else if (bb < 81984) {
    d_pack8_ow1(ow1, dow1, (bb - 8256) * 256 + tid);
  } else if (bb < 83008) {
    d_pack_w(w1, dw1, 1024, 1, (bb - 81984) * 256 + tid);
  } else if (bb < 87616) {
    d_pack_w(ow2, dow2, 256, 9, (bb - 83008) * 256 + tid);
  } else if (bb < 89920) {
    d_pack_w(w2, dw2, 256, 9, (bb - 87616) * 256 + tid);
  } else if (bb < 94528) {
    d_pack_w(ow3, dow3, 256, 9, (bb - 89920) * 256 + tid);
  } else {
    d_pack_w(w3, dw3, 256, 1, (bb - 94528) * 256 + tid);
  }
}

// border-only zero of 3 padded [4][66][66][256] buffers (after off1 is dead)
__global__ __launch_bounds__(256) void border3_k(u16* __restrict__ b0, u16* __restrict__ b1,
                                                 u16* __restrict__ b2) {
  const int id = blockIdx.x * 256 + threadIdx.x;  // < 3*4*260*256 = 798720
  const int buf = id / 266240;
  const int rem = id - buf * 266240;
  const int c = rem & 255;
  const int p = rem >> 8;
  const int b = p / 260;
  const int pi = p - b * 260;
  int y, xx;
  if (pi < 66) { y = 0; xx = pi; }
  else if (pi < 132) { y = 65; xx = pi - 66; }
  else { const int q = pi - 132; y = 1 + (q >> 1); xx = (q & 1) * 65; }
  u16* dst = buf == 0 ? b0 : (buf == 1 ? b1 : b2);
  dst[((size_t)((b * 66 + y) * 66 + xx)) * 256 + c] = 0;
}

// Bilinear resample (per-channel offsets), unchanged.
template <int C, int PADDST>
__global__ __launch_bounds__(256) void deform_k(const u16* __restrict__ src,
                                                const u16* __restrict__ off,
                                                u16* __restrict__ dst) {
  const int id = blockIdx.x * 256 + threadIdx.x;
  const int c = id & (C - 1);
  const int pix = id / C;
  const int b = pix >> 12;
  const int y = (pix >> 6) & 63;
  const int x = pix & 63;
  const unsigned ov = *(const unsigned*)(off + (size_t)pix * (2 * C) + 2 * c);
  const float py = fminf(fmaxf((float)y + h2f((u16)(ov & 0xffffu)), 0.f), 63.f);
  const float px = fminf(fmaxf((float)x + h2f((u16)(ov >> 16)), 0.f), 63.f);
  const int y0i = (int)py, x0i = (int)px;
  const int y1i = min(y0i + 1, 63), x1i = min(x0i + 1, 63);
  const float wy = py - (float)y0i, wx = px - (float)x0i;
  const int bb66 = b * 66;
  auto at = [&](int yi, int xi) -> size_t {
    return ((size_t)((bb66 + yi + 1) * 66 + (xi + 1))) * C + c;
  };
  const float v00 = bf2f(src[at(y0i, x0i)]);
  const float v01 = bf2f(src[at(y0i, x1i)]);
  const float v10 = bf2f(src[at(y1i, x0i)]);
  const float v11 = bf2f(src[at(y1i, x1i)]);
  const float val = v00 * (1.f - wy) * (1.f - wx) + v01 * (1.f - wy) * wx +
                    v10 * wy * (1.f - wx) + v11 * wy * wx;
  const size_t d = PADDST ? at(y, x) : (size_t)id;
  dst[d] = f2bf(val);
}

// ================= 256^2 pipelined offset-conv GEMM, 32x32x16 MFMA ==========
// Skeleton, staging, LDS image, and vmcnt ledger IDENTICAL to round 6 (verified
// in hardware). Only fragment addressing + MFMA shape + epilogue changed.
// Per wave: 128x64 out = 4 m-tiles x 2 n-tiles of 32x32, acc f32x16[4][2].
// A-frag: row=lane&31, kq=ks*2+(lane>>5); B-frag: pix=lane&31, same kq.
template <int TAPS, int CC, int NMT>
__global__ __launch_bounds__(512, 2) void gemm8_conv(
    const u16* __restrict__ Apack, const u16* __restrict__ Bsrc,
    const float* __restrict__ bias, u16* __restrict__ out, int M) {
  constexpr int KT = TAPS * CC / 64;
  constexpr int KT2 = 2 * KT;
  __shared__ u16 lds[65536];
  const int tid = threadIdx.x;
  const int w = tid >> 6, lane = tid & 63;
  const int wm = w >> 2, wn = w & 3;
  const int l31 = lane & 31, l5 = lane >> 5;
  // nt-banded XCD swizzle: XCD j owns nt in [8j, 8j+8), mt fastest.
  const int g = blockIdx.x;
  const int local = g >> 3;
  const int mt = local % NMT;
  const int nt = (g & 7) * 8 + local / NMT;
  const int b_img = nt >> 4;
  const int y0 = (nt & 15) * 4;

  // staging: per-lane offsets precomputed, per-phase scalar base.
  int laneA[2], laneB[2];
  unsigned ldsoff[2];
#pragma unroll
  for (int it = 0; it < 2; ++it) {
    const int d = it * 512 + tid;
    laneA[it] = d * 8;
    const int pl = d >> 2, kq = d & 3;
    const int r = pl >> 6, xc = pl & 63;
    laneB[it] = (r * 66 + xc) * CC + (kq ^ ((pl >> 1) & 3)) * 8;
    ldsoff[it] = (unsigned)(it * 512 + (tid & ~63)) * 8u;
  }
  const u16* Abase = Apack + (size_t)mt * KT2 * 8192;
  const u16* Bbase = Bsrc + (size_t)(b_img * 66 + y0) * 66 * CC;

  f32x16 acc[4][2];
#pragma unroll
  for (int i = 0; i < 4; ++i)
#pragma unroll
    for (int j = 0; j < 2; ++j)
#pragma unroll
      for (int e = 0; e < 16; ++e) acc[i][j][e] = 0.f;

  auto rbase = [&](int b, int op, int kh) -> unsigned {
    return (unsigned)(((b * 2 + op) * 2 + kh) * 8192);
  };
  auto stageA = [&](int H) {
    if (H >= KT2) return;
    const u16* p = Abase + (size_t)H * 8192;
    const unsigned db = rbase((H >> 1) & 1, 0, H & 1);
    gload16(p + laneA[0], (u16*)&lds[db + ldsoff[0]]);
    gload16(p + laneA[1], (u16*)&lds[db + ldsoff[1]]);
  };
  auto stageB = [&](int H) {
    if (H >= KT2) return;
    const int kglob = H * 32;
    const int tap = (TAPS == 1) ? 0 : (kglob / CC);
    const int cbase = kglob - tap * CC;
    const int ky = (TAPS == 9) ? tap / 3 : 0, kx = (TAPS == 9) ? tap % 3 : 0;
    const u16* p = Bbase + (ky * 66 + kx) * CC + cbase;
    const unsigned db = rbase((H >> 1) & 1, 1, H & 1);
    gload16(p + laneB[0], (u16*)&lds[db + ldsoff[0]]);
    gload16(p + laneB[1], (u16*)&lds[db + ldsoff[1]]);
  };

  // frag sets: afE/afO = one tm-pair (tm2 x ks = 4 frags); bfA/bfB = kh's 4.
  bf16x8 afE[4], afO[4], bfA[4], bfB[4];
  auto rdA = [&](bf16x8* dst, int buf, int kh, int tmsel) {
    const unsigned regA = rbase(buf, 0, kh);
#pragma unroll
    for (int tm2 = 0; tm2 < 2; ++tm2)
#pragma unroll
      for (int ks = 0; ks < 2; ++ks) {
        const int row = wm * 128 + (tmsel * 2 + tm2) * 32 + l31;
        const int kq = ks * 2 + l5;
        dst[tm2 * 2 + ks] =
            *(const bf16x8*)&lds[regA + row * 32 + (kq ^ ((row >> 1) & 3)) * 8];
      }
  };
  auto rdB = [&](bf16x8* dst, int buf, int kh) {
    const unsigned regB = rbase(buf, 1, kh);
#pragma unroll
    for (int tn = 0; tn < 2; ++tn)
#pragma unroll
      for (int ks = 0; ks < 2; ++ks) {
        const int p = wn * 64 + tn * 32 + l31;
        const int kq = ks * 2 + l5;
        dst[tn * 2 + ks] =
            *(const bf16x8*)&lds[regB + p * 32 + (kq ^ ((p >> 1) & 3)) * 8];
      }
  };

#define MFMA8(TMSEL_, AF_, BF_)                                                      \
  do {                                                                               \
    __builtin_amdgcn_s_setprio(1);                                                   \
    _Pragma("unroll") for (int tm2 = 0; tm2 < 2; ++tm2)                              \
        _Pragma("unroll") for (int tn = 0; tn < 2; ++tn) {                           \
      acc[TMSEL_ * 2 + tm2][tn] = __builtin_amdgcn_mfma_f32_32x32x16_bf16(           \
          AF_[tm2 * 2 + 0], BF_[tn * 2 + 0], acc[TMSEL_ * 2 + tm2][tn], 0, 0, 0);    \
      acc[TMSEL_ * 2 + tm2][tn] = __builtin_amdgcn_mfma_f32_32x32x16_bf16(           \
          AF_[tm2 * 2 + 1], BF_[tn * 2 + 1], acc[TMSEL_ * 2 + tm2][tn], 0, 0, 0);    \
    }                                                                                \
    __builtin_amdgcn_s_setprio(0);                                                   \
  } while (0)

  // Prologue: stage halves 0..2 (12 loads); VM8 retires half 0; pre-read p=0.
  stageA(0); stageB(0);
  stageA(1); stageB(1);
  stageA(2); stageB(2);
  VM8();
  BAR();
  rdA(afE, 0, 0, 0);
  rdB(bfA, 0, 0);

  for (int t = 0; t < KT; ++t) {
    const int bi = t & 1;
    // ---- sub0: tm{0,1} x kh0 ----
    LGK0();
    rdA(afO, bi, 0, 1);          // tm{2,3} kh0 for sub1
    stageA(2 * t + 3);
    SB0();
    MFMA8(0, afE, bfA);
    if (t >= KT - 2) VM0(); else VM6();   // retires half 2t+1
    BAR();
    // ---- sub1: tm{2,3} x kh0 ----
    LGK0();
    rdA(afE, bi, 1, 0);          // tm{0,1} kh1 for sub2
    rdB(bfB, bi, 1);
    stageB(2 * t + 3);
    SB0();
    MFMA8(1, afO, bfA);
    BAR();
    // ---- sub2: tm{0,1} x kh1 ----
    LGK0();
    rdA(afO, bi, 1, 1);          // tm{2,3} kh1 for sub3
    stageA(2 * t + 4);
    SB0();
    MFMA8(0, afE, bfB);
    if (t < KT - 2) VM6();                // retires half 2t+2
    BAR();
    // ---- sub3: tm{2,3} x kh1 ----
    LGK0();
    if (t + 1 < KT) {
      rdA(afE, bi ^ 1, 0, 0);    // tm{0,1} kh0 of next tile
      rdB(bfA, bi ^ 1, 0);
    }
    stageB(2 * t + 4);
    SB0();
    MFMA8(1, afO, bfB);
    BAR();
  }
#undef MFMA8

  // Epilogue: +bias -> fp16 offsets, NHWC [pix][M].
  // 32x32 C/D (m74/m101): col = lane&31, row = (reg&3) + 8*(reg>>2) + 4*(lane>>5).
#pragma unroll
  for (int tm = 0; tm < 4; ++tm)
#pragma unroll
    for (int tn = 0; tn < 2; ++tn) {
      const int pix = nt * 256 + wn * 64 + tn * 32 + l31;
#pragma unroll
      for (int q = 0; q < 4; ++q) {
        const int oc0 = mt * 256 + wm * 128 + tm * 32 + q * 8 + l5 * 4;
        float r0 = acc[tm][tn][q * 4 + 0] + bias[oc0 + 0];
        float r1 = acc[tm][tn][q * 4 + 1] + bias[oc0 + 1];
        float r2 = acc[tm][tn][q * 4 + 2] + bias[oc0 + 2];
        float r3 = acc[tm][tn][q * 4 + 3] + bias[oc0 + 3];
        uint2 hv;
        hv.x = (unsigned)f2h(r0) | ((unsigned)f2h(r1) << 16);
        hv.y = (unsigned)f2h(r2) | ((unsigned)f2h(r3) << 16);
        *(uint2*)(out + (size_t)pix * M + oc0) = hv;
      }
    }
}

// ================= 128^2 kernel (proven; used for G2..G6) =================
template <int TAPS, int PAD, int EPI, int CC, int WSPLIT>
__global__ __launch_bounds__(256, 2) void gemm_conv(
    const u16* __restrict__ Aph, const u16* __restrict__ Apl,
    const u16* __restrict__ Bh,
    const float* __restrict__ p0, const float* __restrict__ p1,
    const float* __restrict__ p2, const float* __restrict__ p3,
    float* __restrict__ outF, u16* __restrict__ o16a, int M) {
  constexpr int NB = 2 + WSPLIT;
  __shared__ u16 lds[NB * 4096];
  constexpr int steps = TAPS * (CC / 32);
  const int tid = threadIdx.x;
  const int w = tid >> 6, lane = tid & 63;
  const int wm = (w >> 1) * 64, wn = (w & 1) * 64;
  const int kg = lane >> 4, lm = lane & 15;
  const int wg = blockIdx.x;
  const int chunk = (int)(gridDim.x >> 3);
  const int g = (wg & 7) * chunk + (wg >> 3);
  const int mt = g >> 7, nt = g & 127;
  const int b_img = nt >> 5;
  const int y0 = (nt & 31) * 2;

  f32x4 acc[4][4];
  const f32x4 fz = {0.f, 0.f, 0.f, 0.f};
#pragma unroll
  for (int i = 0; i < 4; ++i)
#pragma unroll
    for (int j = 0; j < 4; ++j) acc[i][j] = fz;

  const u16* Abase_h = Aph + (size_t)mt * steps * 4096;
  const u16* Abase_l = WSPLIT ? (Apl + (size_t)mt * steps * 4096) : nullptr;

  for (int step = 0; step < steps; ++step) {
    const int tap = (TAPS == 1) ? 0 : (step / (CC / 32));
    const int c0 = (step - tap * (CC / 32)) * 32;
    const int ky = (TAPS == 9) ? (tap / 3) : 0;
    const int kx = (TAPS == 9) ? (tap % 3) : 0;

#pragma unroll
    for (int it = 0; it < 2; ++it) {
      const int slot = w * 128 + it * 64 + lane;
      const unsigned ldso = (unsigned)(w * 128 + it * 64) * 8u;
      const size_t ga = (size_t)step * 4096 + (size_t)slot * 8;
      gload16(Abase_h + ga, &lds[0 * 4096 + ldso]);
      if (WSPLIT) gload16(Abase_l + ga, &lds[1 * 4096 + ldso]);
      const int n = slot >> 2, kq = slot & 3;
      const int kga = kq ^ ((n >> 1) & 3);
      size_t gb;
      if (PAD) {
        const int r = n >> 6, xc = n & 63;
        gb = ((size_t)((b_img * 66 + (y0 + r + ky)) * 66 + (xc + kx))) * CC +
             (size_t)(c0 + kga * 8);
      } else {
        gb = (size_t)(nt * 128 + n) * CC + (size_t)(c0 + kga * 8);
      }
      gload16(Bh + gb, &lds[(NB - 1) * 4096 + ldso]);
    }
    __syncthreads();

    bf16x8 ah[4], al[4], bh[4];
#pragma unroll
    for (int f = 0; f < 4; ++f) {
      const unsigned ao = (unsigned)(kg * 128 + wm + f * 16 + lm) * 8u;
      ah[f] = *(const bf16x8*)&lds[0 * 4096 + ao];
      if (WSPLIT) al[f] = *(const bf16x8*)&lds[1 * 4096 + ao];
      const int n = wn + f * 16 + lm;
      const unsigned bo = (unsigned)(n * 4 + (kg ^ ((n >> 1) & 3))) * 8u;
      bh[f] = *(const bf16x8*)&lds[(NB - 1) * 4096 + bo];
    }
#pragma unroll
    for (int i = 0; i < 4; ++i)
#pragma unroll
      for (int j = 0; j < 4; ++j) {
        acc[i][j] = __builtin_amdgcn_mfma_f32_16x16x32_bf16(ah[i], bh[j], acc[i][j], 0, 0, 0);
        if (WSPLIT)
          acc[i][j] = __builtin_amdgcn_mfma_f32_16x16x32_bf16(al[i], bh[j], acc[i][j], 0, 0, 0);
      }
    __syncthreads();
  }

  const int ocb = mt * 128 + wm + kg * 4;
#pragma unroll
  for (int fi = 0; fi < 4; ++fi) {
    const int oc0 = ocb + fi * 16;
    f32x4 scl, sft;
    if (EPI == 0) {
#pragma unroll
      for (int j = 0; j < 4; ++j) { scl[j] = 1.f; sft[j] = p0[oc0 + j]; }
    } else {
#pragma unroll
      for (int j = 0; j < 4; ++j) {
        const float inv = p0[oc0 + j] / sqrtf(p3[oc0 + j] + 1e-5f);
        scl[j] = inv;
        sft[j] = p1[oc0 + j] - p2[oc0 + j] * inv;
      }
    }
#pragma unroll
    for (int fj = 0; fj < 4; ++fj) {
      const int pix = nt * 128 + wn + fj * 16 + lm;
      f32x4 r = acc[fi][fj] * scl + sft;
      if (EPI == 0) {
        uint2 hv;
        hv.x = (unsigned)f2h(r[0]) | ((unsigned)f2h(r[1]) << 16);
        hv.y = (unsigned)f2h(r[2]) | ((unsigned)f2h(r[3]) << 16);
        *(uint2*)(o16a + (size_t)pix * M + oc0) = hv;
      } else if (EPI == 1) {
        const int bb = pix >> 12, yy = (pix >> 6) & 63, xx = pix & 63;
        const size_t pp = ((size_t)((bb * 66 + yy + 1) * 66 + (xx + 1))) * M + oc0;
        uint2 hv;
        hv.x = (unsigned)f2bf(r[0]) | ((unsigned)f2bf(r[1]) << 16);
        hv.y = (unsigned)f2bf(r[2]) | ((unsigned)f2bf(r[3]) << 16);
        *(uint2*)(o16a + pp) = hv;
      } else {
        const int bb = pix >> 12, pin = pix & 4095;
#pragma unroll
        for (int j = 0; j < 4; ++j)
          outF[((size_t)(bb * M + oc0 + j)) * 4096 + pin] = fmaxf(r[j], 0.f);
      }
    }
  }
}

extern "C" void kernel_launch(void* const* d_in, const int* in_sizes, int n_in,
                              void* d_out, int out_size, void* d_ws, size_t ws_size,
                              hipStream_t stream) {
  (void)in_sizes; (void)out_size;
  if (n_in < 22) return;
  const float* x   = (const float*)d_in[0];
  const float* ow1 = (const float*)d_in[1];
  const float* ob1 = (const float*)d_in[2];
  const float* ow2 = (const float*)d_in[3];
  const float* ob2 = (const float*)d_in[4];
  const float* ow3 = (const float*)d_in[5];
  const float* ob3 = (const float*)d_in[6];
  const float* w1  = (const float*)d_in[7];
  const float* w2  = (const float*)d_in[8];
  const float* w3  = (const float*)d_in[9];
  const float* g1 = (const float*)d_in[10], *b1 = (const float*)d_in[11];
  const float* m1 = (const float*)d_in[12], *v1 = (const float*)d_in[13];
  const float* g2 = (const float*)d_in[14], *b2 = (const float*)d_in[15];
  const float* m2 = (const float*)d_in[16], *v2 = (const float*)d_in[17];
  const float* g3 = (const float*)d_in[18], *b3 = (const float*)d_in[19];
  const float* m3 = (const float*)d_in[20], *v3 = (const float*)d_in[21];

  char* W = (char*)d_ws;
  // ---- workspace map: 181,043,200 B (identical to round 6; proven safe) ----
  constexpr size_t P66_1024 = 4ull * 66 * 66 * 1024 * 2;
  constexpr size_t P66_256  = 4ull * 66 * 66 * 256 * 2;
  constexpr size_t SZ_OFF1  = 4ull * 4096 * 2048 * 2;
  constexpr size_t SZ_OFF2  = 4ull * 4096 * 512 * 2;
  constexpr size_t SZ_H1    = 4ull * 4096 * 1024 * 2;
  constexpr size_t SZ_H3    = 4ull * 4096 * 256 * 2;
  constexpr size_t SZ_OW1 = 2048ull * 9216 * 2;
  constexpr size_t SZ_W1  = 256ull * 1024 * 2;
  constexpr size_t SZ_OW2 = 512ull * 2304 * 2;
  constexpr size_t SZ_W2  = 256ull * 2304 * 2;
  constexpr size_t SZ_OW3 = 512ull * 2304 * 2;
  constexpr size_t SZ_W3  = 1024ull * 256 * 2;

  constexpr size_t o_ow1h = 0;
  constexpr size_t o_xp   = o_ow1h + SZ_OW1;
  constexpr size_t o_off1 = o_xp + P66_1024;
  constexpr size_t o_t1p  = o_off1;
  constexpr size_t o_off2 = o_t1p + P66_256;
  constexpr size_t o_h2p  = o_off2 + SZ_OFF2;
  constexpr size_t o_t2p  = o_h2p + P66_256;
  static_assert(o_t2p + P66_256 <= o_off1 + SZ_OFF1, "era2 fits off1 slot");
  constexpr size_t o_h1   = o_off1 + SZ_OFF1;
  constexpr size_t o_off3 = o_h1;
  constexpr size_t o_h3   = o_off3 + SZ_OFF2;
  static_assert(o_h3 + SZ_H3 <= o_h1 + SZ_H1, "off3+h3 fit h1 slot");
  constexpr size_t o_w1h  = o_h1 + SZ_H1;
  constexpr size_t o_ow2h = o_w1h + SZ_W1;
  constexpr size_t o_w2h  = o_ow2h + SZ_OW2;
  constexpr size_t o_ow3h = o_w2h + SZ_W2;
  constexpr size_t o_w3h  = o_ow3h + SZ_OW3;
  constexpr size_t WS_NEED = o_w3h + SZ_W3;   // 181,043,200
  if (ws_size < WS_NEED) return;

  auto U = [&](size_t o) { return (u16*)(W + o); };

  // ---- fused prep: packs + x pad + xp borders (one launch) ----
  mega_prep<<<95552, 256, 0, stream>>>(
      x, U(o_xp), ow1, U(o_ow1h), w1, U(o_w1h), ow2, U(o_ow2h),
      w2, U(o_w2h), ow3, U(o_ow3h), w3, U(o_w3h));

  // G1: offset-conv1 (3x3, 1024 -> 2048), 32x32 pipelined -> off1 fp16
  gemm8_conv<9, 1024, 8><<<512, 512, 0, stream>>>(
      U(o_ow1h), U(o_xp), ob1, U(o_off1), 2048);
  // D1: deform(x, off1) -> h1
  deform_k<1024, 0><<<65536, 256, 0, stream>>>(U(o_xp), U(o_off1), U(o_h1));

  // borders of t1p/h2p/t2p (aliases off1 slot -> must be after D1)
  border3_k<<<3120, 256, 0, stream>>>(U(o_t1p), U(o_h2p), U(o_t2p));
  // G2: conv1 1x1 + BN1 -> t1 padded bf16
  gemm_conv<1, 0, 1, 1024, 0><<<256, 256, 0, stream>>>(
      U(o_w1h), nullptr, U(o_h1), g1, b1, m1, v1, nullptr, U(o_t1p), 256);
  // G3: offset-conv2 (3x3, 256 -> 512) -> off2 fp16
  gemm_conv<9, 1, 0, 256, 0><<<512, 256, 0, stream>>>(
      U(o_ow2h), nullptr, U(o_t1p), ob2, nullptr, nullptr, nullptr,
      nullptr, U(o_off2), 512);
  // D2: deform(t1, off2) -> h2 padded
  deform_k<256, 1><<<16384, 256, 0, stream>>>(U(o_t1p), U(o_off2), U(o_h2p));
  // G4: conv2 3x3 + BN2 -> t2 padded bf16
  gemm_conv<9, 1, 1, 256, 0><<<256, 256, 0, stream>>>(
      U(o_w2h), nullptr, U(o_h2p), g2, b2, m2, v2, nullptr, U(o_t2p), 256);
  // G5: offset-conv3 -> off3 fp16
  gemm_conv<9, 1, 0, 256, 0><<<512, 256, 0, stream>>>(
      U(o_ow3h), nullptr, U(o_t2p), ob3, nullptr, nullptr, nullptr,
      nullptr, U(o_off3), 512);
  // D3: deform(t2, off3) -> h3
  deform_k<256, 0><<<16384, 256, 0, stream>>>(U(o_t2p), U(o_off3), U(o_h3));
  // G6: conv3 1x1 + BN3 + ReLU -> d_out (NCHW fp32)
  gemm_conv<1, 0, 2, 256, 0><<<1024, 256, 0, stream>>>(
      U(o_w3h), nullptr, U(o_h3), g3, b3, m3, v3, (float*)d_out, nullptr, 1024);
}